// Round 1
// baseline (960.121 us; speedup 1.0000x reference)
//
#include <hip/hip_runtime.h>

#define LL 8
#define BB 32
#define SS 512
#define DD 256
#define EE 2048
#define LED (LL*DD*EE)   // 4194304
#define LE  (LL*EE)      // 16384
#define NROWS (BB*LL*SS) // 131072
#define NKS 17           // 16 real K-steps + 1 norm-fold K-step

typedef __bf16 bf16x8 __attribute__((ext_vector_type(8)));
typedef float  f32x16 __attribute__((ext_vector_type(16)));

// ---------------------------------------------------------------------------
// Kernel 1: transpose embed (L,D,E) -> embed_t (L,E,D) and accumulate norms
// ---------------------------------------------------------------------------
__global__ void transpose_norms_kernel(const float* __restrict__ embed,
                                       float* __restrict__ embed_t,
                                       float* __restrict__ norms) {
    __shared__ float tile[32][33];
    const int l  = blockIdx.z;
    const int d0 = blockIdx.y * 32;
    const int e0 = blockIdx.x * 32;
    const int tx = threadIdx.x, ty = threadIdx.y;

    float v = embed[((size_t)l*DD + d0 + ty)*EE + e0 + tx];
    tile[ty][tx] = v;
    __syncthreads();
    embed_t[((size_t)l*EE + e0 + ty)*DD + d0 + tx] = tile[tx][ty];
    __syncthreads();
    tile[ty][tx] = v * v;
    __syncthreads();
    if (ty == 0) {
        float s = 0.f;
        #pragma unroll
        for (int i = 0; i < 32; ++i) s += tile[i][tx];
        atomicAdd(&norms[l*EE + e0 + tx], s);
    }
}

// ---------------------------------------------------------------------------
// Kernel 1b: embed -> MFMA A-fragment-ordered bf16 hi/lo (+ norm fold K-step)
// ---------------------------------------------------------------------------
__global__ void prep_embed_frag(const float* __restrict__ embed,
                                const float* __restrict__ norms,
                                __bf16* __restrict__ frag) {
    const int bid   = blockIdx.x;
    const int kstep = bid % NKS;
    const int mtile = (bid / NKS) % 64;
    const int l     = bid / (NKS * 64);
    const int lane  = threadIdx.x;
    const int e     = mtile*32 + (lane & 31);
    const int kbase = kstep*16 + (lane >> 5)*8;

    bf16x8 vh, vl;
    if (kstep < 16) {
        #pragma unroll
        for (int j = 0; j < 8; ++j) {
            float v = embed[((size_t)l*DD + kbase + j)*EE + e];
            __bf16 h = (__bf16)v;
            vh[j] = h;
            vl[j] = (__bf16)(v - (float)h);
        }
    } else {
        #pragma unroll
        for (int j = 0; j < 8; ++j) { vh[j] = (__bf16)0.0f; vl[j] = (__bf16)0.0f; }
        if (kbase == 256) {
            float nv = -0.5f * norms[l*EE + e];
            __bf16 ch = (__bf16)nv;
            vh[0] = ch;
            vh[1] = (__bf16)(nv - (float)ch);
        }
    }
    size_t base = ((((size_t)l*64 + mtile)*2 + 0)*NKS + kstep)*64 + lane;
    *(bf16x8*)(frag + base*8) = vh;
    base = ((((size_t)l*64 + mtile)*2 + 1)*NKS + kstep)*64 + lane;
    *(bf16x8*)(frag + base*8) = vl;
}

// ---------------------------------------------------------------------------
// Kernel 2: MFMA argmin + fused counts histogram + fused q-gather/out/diff.
// 3 independent accumulator chains to break the 51-deep MFMA dependency chain.
// ---------------------------------------------------------------------------
__global__ __launch_bounds__(256, 2)
void argmin_mfma(const float* __restrict__ x,
                 const __bf16* __restrict__ frag,
                 const float* __restrict__ embed_t,
                 int* __restrict__ ids_out,
                 int* __restrict__ counts_i,
                 float* __restrict__ out,
                 float* __restrict__ diff_acc) {
    __shared__ __bf16 smem[2][2*NKS*512];    // 68 KB

    const int tid  = threadIdx.x;
    const int wave = tid >> 6, lane = tid & 63;
    const int l    = blockIdx.x & 7;
    const int rb   = blockIdx.x >> 3;
    const int idx  = rb*4 + wave;
    const int b    = idx >> 4, st = idx & 15;
    const int rowtile = (b*LL + l)*16 + st;

    bf16x8 bh[NKS], bl[16];
    {
        const float* xr = x + (size_t)(rowtile*32 + (lane & 31))*DD + (lane >> 5)*8;
        #pragma unroll
        for (int ks = 0; ks < 16; ++ks) {
            float4 v0 = *(const float4*)(xr + ks*16);
            float4 v1 = *(const float4*)(xr + ks*16 + 4);
            float f[8] = {v0.x, v0.y, v0.z, v0.w, v1.x, v1.y, v1.z, v1.w};
            #pragma unroll
            for (int j = 0; j < 8; ++j) {
                __bf16 h = (__bf16)f[j];
                bh[ks][j] = h;
                bl[ks][j] = (__bf16)(f[j] - (float)h);
            }
        }
        #pragma unroll
        for (int j = 0; j < 8; ++j) bh[16][j] = (__bf16)0.0f;
        if (lane < 32) { bh[16][0] = (__bf16)1.0f; bh[16][1] = (__bf16)1.0f; }
    }

    const __bf16* fl = frag + (size_t)l*64*2*NKS*512;

    auto stage = [&](int m, int buf) {
        const __bf16* src = fl + (size_t)m*2*NKS*512;
        __bf16* dst = &smem[buf][0];
        for (int i = wave; i < 2*NKS; i += 4) {
            __builtin_amdgcn_global_load_lds(
                (const __attribute__((address_space(1))) void*)(src + i*512 + lane*8),
                (__attribute__((address_space(3))) void*)(dst + i*512), 16, 0, 0);
        }
    };

    float maxv = -3.4e38f;
    int   maxi = 0;

    stage(0, 0);
    __syncthreads();
    for (int m = 0; m < 64; ++m) {
        const int buf = m & 1;
        if (m < 63) stage(m + 1, buf ^ 1);
        const __bf16* sA = &smem[buf][0];
        f32x16 a0, a1, a2;
        #pragma unroll
        for (int i = 0; i < 16; ++i) { a0[i] = 0.0f; a1[i] = 0.0f; a2[i] = 0.0f; }
        #pragma unroll
        for (int ks = 0; ks < 16; ++ks) {
            bf16x8 ah = *(const bf16x8*)(sA + ks*512 + lane*8);
            bf16x8 al = *(const bf16x8*)(sA + (NKS + ks)*512 + lane*8);
            a0 = __builtin_amdgcn_mfma_f32_32x32x16_bf16(ah, bh[ks], a0, 0, 0, 0);
            a1 = __builtin_amdgcn_mfma_f32_32x32x16_bf16(ah, bl[ks], a1, 0, 0, 0);
            a2 = __builtin_amdgcn_mfma_f32_32x32x16_bf16(al, bh[ks], a2, 0, 0, 0);
        }
        {   // norm-fold K-step: norm hi+lo both live in ah*bh; other terms are 0
            bf16x8 ah = *(const bf16x8*)(sA + 16*512 + lane*8);
            a0 = __builtin_amdgcn_mfma_f32_32x32x16_bf16(ah, bh[16], a0, 0, 0, 0);
        }
        const int ebase = m*32 + 4*(lane >> 5);
        #pragma unroll
        for (int r = 0; r < 16; ++r) {
            float v = a0[r] + a1[r] + a2[r];
            int e = ebase + (r & 3) + 8*(r >> 2);
            // e is visited in ascending order per lane -> strict > keeps smallest e on ties
            if (v > maxv) { maxv = v; maxi = e; }
        }
        __syncthreads();
    }
    float ov = __shfl_xor(maxv, 32, 64);
    int   oi = __shfl_xor(maxi, 32, 64);
    if (ov > maxv || (ov == maxv && oi < maxi)) { maxv = ov; maxi = oi; }
    if (lane < 32) {
        ids_out[(size_t)rowtile*32 + lane] = maxi;
        atomicAdd(&counts_i[l*EE + maxi], 1);
    }

    // ---- fused gather q -> out (+ diff partial for l == L-1) ----
    const float4* et4  = (const float4*)embed_t;
    const float4* x4   = (const float4*)x;
    float4*       out4 = (float4*)out;
    float sq = 0.f;
    #pragma unroll 4
    for (int r = 0; r < 32; ++r) {
        int id = __shfl(maxi, r);   // all 64 lanes hold row r's result after combine
        float4 qv = et4[((size_t)l*EE + id)*64 + lane];
        size_t o = ((size_t)rowtile*32 + r)*64 + lane;
        out4[o] = qv;
        if (l == LL - 1) {
            float4 xv = x4[o];
            float dx = qv.x - xv.x, dy = qv.y - xv.y, dz = qv.z - xv.z, dw = qv.w - xv.w;
            sq += dx*dx + dy*dy + dz*dz + dw*dw;
        }
    }
    if (l == LL - 1) {
        #pragma unroll
        for (int off = 32; off; off >>= 1) sq += __shfl_down(sq, off);
        if (lane == 0) atomicAdd(diff_acc, sq);
    }
}

// ---------------------------------------------------------------------------
// Kernel 2b: per-l exclusive scan of counts -> bin_start, cursor
//            + fused new_cluster_size & per-l sum n (was finalize_cluster)
// ---------------------------------------------------------------------------
__global__ __launch_bounds__(256)
void scan_kernel(const int* __restrict__ counts_i,
                 const float* __restrict__ cs_in,
                 int* __restrict__ bin_start,
                 int* __restrict__ cursor,
                 float* __restrict__ ncs_out,
                 float* __restrict__ n_out) {
    __shared__ int part[256];
    __shared__ float red[4];
    const int l = blockIdx.x, tid = threadIdx.x;
    const int base = l*EE + tid*8;
    int local[8], tsum = 0;
    float fsum = 0.f;
    #pragma unroll
    for (int j = 0; j < 8; ++j) {
        local[j] = counts_i[base + j];
        tsum += local[j];
        float v = 0.999f*cs_in[base + j] + 0.001f*(float)local[j];
        ncs_out[base + j] = v;
        fsum += v;
    }
    part[tid] = tsum;
    __syncthreads();
    for (int off = 1; off < 256; off <<= 1) {
        int v = (tid >= off) ? part[tid - off] : 0;
        __syncthreads();
        part[tid] += v;
        __syncthreads();
    }
    int run = part[tid] - tsum;
    #pragma unroll
    for (int j = 0; j < 8; ++j) {
        bin_start[base + j] = run;
        cursor[base + j]    = run;
        run += local[j];
    }
    #pragma unroll
    for (int off = 32; off; off >>= 1) fsum += __shfl_down(fsum, off);
    if ((tid & 63) == 0) red[tid >> 6] = fsum;
    __syncthreads();
    if (tid == 0) n_out[l] = red[0] + red[1] + red[2] + red[3];
}

// ---------------------------------------------------------------------------
// Kernel 2c: scatter row indices into per-l sorted order
// ---------------------------------------------------------------------------
__global__ __launch_bounds__(256)
void scatter_idx_kernel(const int* __restrict__ ids,
                        int* __restrict__ cursor,
                        int* __restrict__ sorted_rows) {
    const int r = blockIdx.x*256 + threadIdx.x;
    const int l = (r >> 9) & 7;
    const int e = ids[r];
    int pos = atomicAdd(&cursor[l*EE + e], 1);
    sorted_rows[l*(NROWS/LL) + pos] = r;
}

// ---------------------------------------------------------------------------
// Kernel 2d: segmented sum — one block per (l,e), threads = d
// ---------------------------------------------------------------------------
__global__ __launch_bounds__(256)
void segsum_kernel(const float* __restrict__ x,
                   const int* __restrict__ sorted_rows,
                   const int* __restrict__ bin_start,
                   const int* __restrict__ counts_i,
                   float* __restrict__ embed_sum) {
    const int bid = blockIdx.x;
    const int l   = bid >> 11;
    const int e   = bid & 2047;
    const int tid = threadIdx.x;
    const int start = bin_start[l*EE + e];
    const int cnt   = counts_i[l*EE + e];
    const int* rows = sorted_rows + l*(NROWS/LL);

    float acc = 0.f;
    int i = 0;
    for (; i + 1 < cnt; i += 2) {
        int r0 = rows[start + i], r1 = rows[start + i + 1];
        acc += x[(size_t)r0*DD + tid] + x[(size_t)r1*DD + tid];
    }
    if (i < cnt) acc += x[(size_t)rows[start + i]*DD + tid];
    embed_sum[((size_t)l*EE + e)*DD + tid] = acc;
}

// ---------------------------------------------------------------------------
// Kernel 5: new_embed_avg + new_embed
// ---------------------------------------------------------------------------
__global__ void finalize_embed_kernel(const float* __restrict__ embed_avg,
                                      const float* __restrict__ embed_sum,
                                      const float* __restrict__ ncs,
                                      const float* __restrict__ n,
                                      float* __restrict__ nea_out,
                                      float* __restrict__ ne_out) {
    __shared__ float tile[32][33];
    const int l  = blockIdx.z;
    const int d0 = blockIdx.y * 32;
    const int e0 = blockIdx.x * 32;
    const int tx = threadIdx.x, ty = threadIdx.y;

    tile[ty][tx] = embed_sum[((size_t)l*EE + e0 + ty)*DD + d0 + tx];
    __syncthreads();
    const size_t idx = ((size_t)l*DD + d0 + ty)*EE + e0 + tx;
    float nea = 0.999f*embed_avg[idx] + 0.001f*tile[tx][ty];
    nea_out[idx] = nea;
    float nl = n[l];
    float c  = ncs[l*EE + e0 + tx];
    float cs = (c + 1e-5f) / (nl + 0.02048f) * nl;
    ne_out[idx] = nea / cs;
}

// ---------------------------------------------------------------------------
// Kernel 6: diff scale
// ---------------------------------------------------------------------------
__global__ void diff_scale_kernel(const float* __restrict__ diff_acc,
                                  float* __restrict__ diff_out) {
    *diff_out = (*diff_acc / (float)(BB*SS*DD)) * 0.25f;
}

// ---------------------------------------------------------------------------
extern "C" void kernel_launch(void* const* d_in, const int* in_sizes, int n_in,
                              void* d_out, int out_size, void* d_ws, size_t ws_size,
                              hipStream_t stream) {
    const float* x            = (const float*)d_in[0];
    const float* embed        = (const float*)d_in[1];
    const float* cluster_size = (const float*)d_in[2];
    const float* embed_avg    = (const float*)d_in[3];

    float* out      = (float*)d_out;
    float* diff_out = out + 33554432;
    int*   ids_out  = (int*)(out + 33554433);
    float* ne_out   = out + 33685505;
    float* ncs_out  = out + 37879809;
    float* nea_out  = out + 37896193;

    float* ws        = (float*)d_ws;
    float* embed_t   = ws;                          // LED floats
    float* embed_sum = ws + LED;                    // LED floats (fully written by segsum)
    int*   counts_i  = (int*)(ws + 2*(size_t)LED);  // LE ints   (zeroed)
    float* norms     = ws + 2*(size_t)LED + LE;     // LE floats (zeroed)
    float* diff_acc  = norms + LE;                  // 1 float   (zeroed)
    float* n_ws      = diff_acc + 1;                // LL floats
    int*   bin_start = (int*)(n_ws + LL);           // LE ints
    int*   cursor    = bin_start + LE;              // LE ints
    int*   sorted_rows = cursor + LE;               // NROWS ints
    __bf16* embfrag  = (__bf16*)(sorted_rows + NROWS + 16);  // 8.9M bf16

    // zero: counts_i, norms, diff_acc (contiguous)
    hipMemsetAsync(counts_i, 0, (size_t)(2*LE + 1) * sizeof(float), stream);

    transpose_norms_kernel<<<dim3(EE/32, DD/32, LL), dim3(32, 32), 0, stream>>>(
        embed, embed_t, norms);

    prep_embed_frag<<<LL*64*NKS, 64, 0, stream>>>(embed, norms, embfrag);

    argmin_mfma<<<1024, 256, 0, stream>>>(x, embfrag, embed_t, ids_out, counts_i,
                                          out, diff_acc);

    scan_kernel<<<LL, 256, 0, stream>>>(counts_i, cluster_size, bin_start, cursor,
                                        ncs_out, n_ws);

    scatter_idx_kernel<<<NROWS/256, 256, 0, stream>>>(ids_out, cursor, sorted_rows);

    segsum_kernel<<<LE, 256, 0, stream>>>(x, sorted_rows, bin_start, counts_i, embed_sum);

    finalize_embed_kernel<<<dim3(EE/32, DD/32, LL), dim3(32, 32), 0, stream>>>(
        embed_avg, embed_sum, ncs_out, n_ws, nea_out, ne_out);

    diff_scale_kernel<<<1, 1, 0, stream>>>(diff_acc, diff_out);
}